// Round 6
// baseline (244.937 us; speedup 1.0000x reference)
//
#include <hip/hip_runtime.h>

// Problem constants: B=4, S=2048, D=1024
#define BB 4
#define SS 2048
#define DD 1024

typedef __attribute__((ext_vector_type(8))) _Float16 half8;
typedef __attribute__((ext_vector_type(4))) float f32x4;
typedef unsigned short ushort_t;

// fp32 -> fp16 (RTN via v_cvt_f16_f32), returned as raw bits
__device__ __forceinline__ ushort_t f2h(float f) {
    union { _Float16 h; ushort_t u; } c;
    c.h = (_Float16)f;
    return c.u;
}

union Pack8 { ushort_t u[8]; uint4 v; };

// ---------------------------------------------------------------------------
// K0: fp32 -> fp16 convert for BOTH Q(enc) and K(att) in one launch.
// grid = (4096, 2); y=0: enc->Qb, y=1: att->Kb. 8 elems/thread.
// ---------------------------------------------------------------------------
__global__ __launch_bounds__(256) void conv_h_qk(const float* __restrict__ enc,
                                                 const float* __restrict__ att,
                                                 ushort_t* __restrict__ Qb,
                                                 ushort_t* __restrict__ Kb) {
    const float* in = blockIdx.y ? att : enc;
    ushort_t* out   = blockIdx.y ? Kb : Qb;
    long i = ((long)blockIdx.x * 256 + threadIdx.x) * 8;
    float4 a = *(const float4*)(in + i);
    float4 b = *(const float4*)(in + i + 4);
    Pack8 p;
    p.u[0] = f2h(a.x); p.u[1] = f2h(a.y); p.u[2] = f2h(a.z); p.u[3] = f2h(a.w);
    p.u[4] = f2h(b.x); p.u[5] = f2h(b.y); p.u[6] = f2h(b.z); p.u[7] = f2h(b.w);
    *(uint4*)(out + i) = p.v;
}

// ---------------------------------------------------------------------------
// GEMM (bt form): C[m][n] = sum_k A[m][k] * B[n][k], A/B fp16 row-major,
// C fp32. 128x128 tile, BK=64, 4 waves, 16x16x32 f16 MFMA, global_load_lds
// (16B) with XOR swizzle (linear LDS dest + inverse-swizzled global source +
// swizzled ds_read_b128 — rule #21's both-sides-or-neither).
// ---------------------------------------------------------------------------
__global__ __launch_bounds__(256, 2)
void gemm_bt(const ushort_t* __restrict__ A, const ushort_t* __restrict__ Bm,
             float* __restrict__ C, int M, int N, int Kd,
             long sAb, long sBb, long sCb) {
    __shared__ ushort_t Abuf[128 * 64];   // 16 KiB, row = 128 B
    __shared__ ushort_t Bbuf[128 * 64];   // 16 KiB

    const int t = threadIdx.x;
    const int w = t >> 6, lane = t & 63;
    const int wr = w >> 1, wc = w & 1;
    const int m0 = blockIdx.x << 7;
    const int n0 = blockIdx.y << 7;
    const int bz = blockIdx.z;

    const ushort_t* Ab = A + (long)bz * sAb;
    const ushort_t* Bb = Bm + (long)bz * sBb;
    float* Cb = C + (long)bz * sCb;

    f32x4 zero = {0.f, 0.f, 0.f, 0.f};
    f32x4 acc[4][4];
    #pragma unroll
    for (int i = 0; i < 4; ++i)
        #pragma unroll
        for (int j = 0; j < 4; ++j) acc[i][j] = zero;

    const int rloc = lane >> 3;          // row within 8-row chunk
    const int rho  = (lane & 7) << 4;    // byte col within 128B row

    const int nkt = Kd >> 6;
    for (int kt = 0; kt < nkt; ++kt) {
        const int k0 = kt << 6;
        __syncthreads();  // previous compute done before LDS overwrite
        #pragma unroll
        for (int i = 0; i < 4; ++i) {
            int c = (w << 2) | i;              // chunk 0..15 (1 KiB each)
            int r = (c << 3) + rloc;           // tile row 0..127
            int rs = rho ^ ((r & 7) << 4);     // inverse-swizzled source col
            const char* src = (const char*)(Ab + (long)(m0 + r) * Kd + k0) + rs;
            __builtin_amdgcn_global_load_lds(
                (__attribute__((address_space(1))) void*)src,
                (__attribute__((address_space(3))) void*)((char*)Abuf + (c << 10)),
                16, 0, 0);
        }
        #pragma unroll
        for (int i = 0; i < 4; ++i) {
            int c = (w << 2) | i;
            int r = (c << 3) + rloc;
            int rs = rho ^ ((r & 7) << 4);
            const char* src = (const char*)(Bb + (long)(n0 + r) * Kd + k0) + rs;
            __builtin_amdgcn_global_load_lds(
                (__attribute__((address_space(1))) void*)src,
                (__attribute__((address_space(3))) void*)((char*)Bbuf + (c << 10)),
                16, 0, 0);
        }
        __syncthreads();  // drains vmcnt -> tile ready

        #pragma unroll
        for (int kk = 0; kk < 64; kk += 32) {
            const int colb = (kk + ((lane >> 4) << 3)) << 1;  // byte col base
            half8 af[4], bf[4];
            #pragma unroll
            for (int am = 0; am < 4; ++am) {
                int rA = (wr << 6) + (am << 4) + (lane & 15);
                int addr = (rA << 7) + (colb ^ ((rA & 7) << 4));
                af[am] = *(const half8*)((const char*)Abuf + addr);
            }
            #pragma unroll
            for (int bn = 0; bn < 4; ++bn) {
                int rB = (wc << 6) + (bn << 4) + (lane & 15);
                int addr = (rB << 7) + (colb ^ ((rB & 7) << 4));
                bf[bn] = *(const half8*)((const char*)Bbuf + addr);
            }
            #pragma unroll
            for (int am = 0; am < 4; ++am)
                #pragma unroll
                for (int bn = 0; bn < 4; ++bn)
                    acc[am][bn] = __builtin_amdgcn_mfma_f32_16x16x32_f16(
                        af[am], bf[bn], acc[am][bn], 0, 0, 0);
        }
    }

    // epilogue: D row = (lane>>4)*4 + j, col = lane&15  [m89 verified layout]
    #pragma unroll
    for (int am = 0; am < 4; ++am) {
        int mrow = m0 + (wr << 6) + (am << 4) + ((lane >> 4) << 2);
        #pragma unroll
        for (int bn = 0; bn < 4; ++bn) {
            int ncol = n0 + (wc << 6) + (bn << 4) + (lane & 15);
            #pragma unroll
            for (int j = 0; j < 4; ++j)
                Cb[(long)(mrow + j) * N + ncol] = acc[am][bn][j];
        }
    }
}

// ---------------------------------------------------------------------------
// K2: row softmax over k (2048 fp32), write P as fp16 in-place over the row.
// One block (256 thr) per row; 8 elems/thread kept in registers.
// All row reads complete before the first barrier; the fp16 write (bytes
// [16t,16t+16) within the row) happens after the last barrier — race-free.
// ---------------------------------------------------------------------------
__device__ __forceinline__ float wred_max(float v) {
    #pragma unroll
    for (int o = 32; o > 0; o >>= 1) v = fmaxf(v, __shfl_xor(v, o, 64));
    return v;
}
__device__ __forceinline__ float wred_sum(float v) {
    #pragma unroll
    for (int o = 32; o > 0; o >>= 1) v += __shfl_xor(v, o, 64);
    return v;
}

__global__ __launch_bounds__(256) void softmax_rows(float* __restrict__ score) {
    __shared__ float red[4];
    __shared__ float bc[2];
    const long row = blockIdx.x;
    float* rp = score + row * (long)SS;
    const int t = threadIdx.x, w = t >> 6, lane = t & 63;

    float4 v0 = ((const float4*)rp)[t * 2];
    float4 v1 = ((const float4*)rp)[t * 2 + 1];
    float f[8] = {v0.x, v0.y, v0.z, v0.w, v1.x, v1.y, v1.z, v1.w};

    float m = f[0];
    #pragma unroll
    for (int j = 1; j < 8; ++j) m = fmaxf(m, f[j]);
    m = wred_max(m);
    if (lane == 0) red[w] = m;
    __syncthreads();
    if (t == 0) bc[0] = fmaxf(fmaxf(red[0], red[1]), fmaxf(red[2], red[3]));
    __syncthreads();
    m = bc[0];

    float e[8], s = 0.f;
    #pragma unroll
    for (int j = 0; j < 8; ++j) { e[j] = __expf(f[j] - m); s += e[j]; }
    s = wred_sum(s);
    if (lane == 0) red[w] = s;
    __syncthreads();
    if (t == 0) bc[1] = red[0] + red[1] + red[2] + red[3];
    __syncthreads();
    const float inv = 1.f / bc[1];

    Pack8 p;
    #pragma unroll
    for (int j = 0; j < 8; ++j) p.u[j] = f2h(e[j] * inv);
    ((uint4*)rp)[t] = p.v;
}

// ---------------------------------------------------------------------------
// K3: transpose P (fp16 bits, src row stride 4096 ushorts in score buffer)
//     Pt[b][n][q] = P[b][q][n].  64x64 tiles via LDS.
// ---------------------------------------------------------------------------
__global__ __launch_bounds__(256) void transposeP(const ushort_t* __restrict__ Pb,
                                                  ushort_t* __restrict__ Pt) {
    __shared__ ushort_t lds[64][72];  // 144B rows: 16B-aligned, bank-shifted
    const int b = blockIdx.z;
    const int n0 = blockIdx.x << 6, q0 = blockIdx.y << 6;
    const int t = threadIdx.x, rh = t >> 3, cb = (t & 7) << 3;

    #pragma unroll
    for (int it = 0; it < 2; ++it) {
        int r = (it << 5) + rh;
        const ushort_t* src = Pb + ((long)(b * SS + q0 + r)) * 4096 + n0 + cb;
        *(uint4*)&lds[r][cb] = *(const uint4*)src;
    }
    __syncthreads();
    #pragma unroll
    for (int it = 0; it < 2; ++it) {
        int rr = (it << 5) + rh;
        Pack8 p;
        #pragma unroll
        for (int j = 0; j < 8; ++j) p.u[j] = lds[cb + j][rr];
        *(uint4*)(Pt + ((long)b * SS + n0 + rr) * (long)SS + q0 + cb) = p.v;
    }
}

// ---------------------------------------------------------------------------
// K4: Xbt[b][d][q] = fp16(enc[b][q][d] + res[b][q][d])  (transpose+add+cast)
// ---------------------------------------------------------------------------
__global__ __launch_bounds__(256) void transposeX(const float* __restrict__ enc,
                                                  const float* __restrict__ res,
                                                  ushort_t* __restrict__ Xbt) {
    __shared__ ushort_t lds[64][72];
    const int b = blockIdx.z;
    const int q0 = blockIdx.x << 6, d0 = blockIdx.y << 6;
    const int t = threadIdx.x, rh = t >> 3, cb = (t & 7) << 3;

    #pragma unroll
    for (int it = 0; it < 2; ++it) {
        int r = (it << 5) + rh;
        long base = ((long)b * SS + q0 + r) * (long)DD + d0 + cb;
        float4 a0 = *(const float4*)(enc + base);
        float4 a1 = *(const float4*)(enc + base + 4);
        float4 b0 = *(const float4*)(res + base);
        float4 b1 = *(const float4*)(res + base + 4);
        Pack8 p;
        p.u[0] = f2h(a0.x + b0.x); p.u[1] = f2h(a0.y + b0.y);
        p.u[2] = f2h(a0.z + b0.z); p.u[3] = f2h(a0.w + b0.w);
        p.u[4] = f2h(a1.x + b1.x); p.u[5] = f2h(a1.y + b1.y);
        p.u[6] = f2h(a1.z + b1.z); p.u[7] = f2h(a1.w + b1.w);
        *(uint4*)&lds[r][cb] = p.v;
    }
    __syncthreads();
    #pragma unroll
    for (int it = 0; it < 2; ++it) {
        int rr = (it << 5) + rh;  // d-local
        Pack8 p;
        #pragma unroll
        for (int j = 0; j < 8; ++j) p.u[j] = lds[cb + j][rr];
        *(uint4*)(Xbt + ((long)b * DD + d0 + rr) * (long)SS + q0 + cb) = p.v;
    }
}

// ---------------------------------------------------------------------------
// Workspace layout (96 MiB total, overlapped lifetimes):
//   [0, 64 MiB)   score fp32 [B][S][S] (GEMM1 out, softmax in/out as fp16 P)
//                 -> DEAD after transposeP -> reused as Xbt fp16 [B][D][S]
//   [64, 96 MiB)  Qb fp16 + Kb fp16 (GEMM1 in) -> DEAD after GEMM1
//                 -> reused as Pt fp16 [B][S][S]
// Stream ordering makes every overlap safe.
// ---------------------------------------------------------------------------
extern "C" void kernel_launch(void* const* d_in, const int* in_sizes, int n_in,
                              void* d_out, int out_size, void* d_ws, size_t ws_size,
                              hipStream_t stream) {
    const float* enc = (const float*)d_in[0];
    const float* att = (const float*)d_in[1];
    const float* res = (const float*)d_in[2];
    float* out = (float*)d_out;
    char* ws = (char*)d_ws;

    float*    score = (float*)ws;                                  // 67108864 B
    ushort_t* Qb    = (ushort_t*)(ws + 67108864);                  // 16777216 B
    ushort_t* Kb    = (ushort_t*)(ws + 67108864 + 16777216);       // 16777216 B
    ushort_t* Pt    = (ushort_t*)(ws + 67108864);                  // overlays Qb/Kb
    ushort_t* Xbt   = (ushort_t*)ws;                               // overlays score

    // K0: convert Q (enc) and K (att) to fp16 (one launch)
    conv_h_qk<<<dim3(4096, 2), 256, 0, stream>>>(enc, att, Qb, Kb);

    // K1: score[b][q][k] = Q . K   (M=N=2048, Kd=1024)
    gemm_bt<<<dim3(16, 16, BB), 256, 0, stream>>>(
        Qb, Kb, score, SS, SS, DD,
        (long)SS * DD, (long)SS * DD, (long)SS * SS);

    // K2: softmax rows, P fp16 in place
    softmax_rows<<<BB * SS, 256, 0, stream>>>(score);

    // K3: Pt[b][k][q] = P[b][q][k]   (Qb/Kb dead from here)
    transposeP<<<dim3(32, 32, BB), 256, 0, stream>>>((const ushort_t*)score, Pt);

    // K4: Xbt[b][d][q] = fp16(enc + res)   (score dead from here)
    transposeX<<<dim3(32, 16, BB), 256, 0, stream>>>(enc, res, Xbt);

    // K5: out[b][k][d] = sum_q Pt[k][q] * Xbt[d][q]  (M=2048, N=1024, Kd=2048)
    gemm_bt<<<dim3(16, 8, BB), 256, 0, stream>>>(
        Pt, Xbt, out, SS, DD, SS,
        (long)SS * SS, (long)DD * SS, (long)SS * DD);
}